// Round 13
// baseline (631.017 us; speedup 1.0000x reference)
//
#include <hip/hip_runtime.h>
#include <hip/hip_bf16.h>
#include <stdint.h>
#include <math.h>

// PANConcDQL round 13 -- math identical to round 12 (passed, absmax 0.0).
// Change: all 8 compute kernels fused into ONE persistent 256-block kernel
// with device-scope global barriers between phases (dispatch-floor removal).
#define BB   16
#define NPn  512
#define LLp  20
#define NAa  50
#define KKk  410
#define NNt  (BB * NPn)   // 8192
#define EEe  (6 * NNt)    // 49152
#define NFf  13
#define KPAD 416
#define EPSf 1e-5f
#define QCLMP 1e6f
#define MAXD 28
#define PADR 512
#define NBLK 256

__device__ __forceinline__ float r13_sane(float v) {
    if (!(v == v)) return 0.0f;
    return fminf(fmaxf(v, -1e15f), 1e15f);
}

// device-scope grid barrier: all NBLK blocks are co-resident (LDS 34KB ->
// >=1 block/CU at any VGPR count; 256 slots >= 256 blocks -> no deadlock).
__device__ __forceinline__ void r13_bar(uint32_t* cnt, uint32_t gen) {
    __threadfence();                    // release this block's writes (agent scope)
    __syncthreads();                    // all threads fenced before arrival
    if (threadIdx.x == 0) {
        atomicAdd(cnt, 1u);
        while (atomicAdd(cnt, 0u) < gen * NBLK) { __builtin_amdgcn_s_sleep(8); }
    }
    __syncthreads();
    __threadfence();                    // acquire: invalidate for fresh reads
}

__global__ __launch_bounds__(512) void r13_mega(
    const float* __restrict__ x,
    const int* __restrict__ ei,
    const int* __restrict__ cnid,
    const int* __restrict__ amask,
    const float* __restrict__ panw,
    const float* __restrict__ l1w, const float* __restrict__ l1b,
    const float* n1w, const float* n1b, const float* n1ms,
    const float* poolp, const float* poolb,
    const float* gwl, const float* gbl,
    const float* gwr, const float* gbr,
    const float* gatt, const float* gbias,
    const float* n2w, const float* n2b, const float* n2ms,
    const float* v1w, const float* v1b,
    const float* v2w, const float* v2b,
    const float* v3w, const float* v3b,
    const float* a1w, const float* a1b,
    const float* a2w, const float* a2b,
    const float* a3w, const float* a3b,
    uint32_t* __restrict__ fwdb, uint32_t* __restrict__ trsb,   // trsb aliased as Rb
    uint32_t* __restrict__ cnt,
    unsigned short* __restrict__ csrF, unsigned short* __restrict__ csrT,
    float* __restrict__ h_raw, float* __restrict__ x1,
    float* __restrict__ colsum, float* __restrict__ disv,
    float* __restrict__ xp, float* __restrict__ g_raw,
    int* __restrict__ kept,
    float* __restrict__ out)
{
    __shared__ __align__(16) float smf[8704];      // 34816 B union, reused per phase
    const int B = blockIdx.x, t = threadIdx.x;
    const int gtid = B * 512 + t;
    uint32_t* Rb = trsb;

    // ---------------- P1: edge scatter -> global bitsets ----------------
    if (gtid < EEe) {
        const int src = ei[gtid], dst = ei[EEe + gtid];
        atomicOr(&fwdb[(size_t)dst * 16 + ((src & 511) >> 5)], 1u << (src & 31));
        atomicOr(&trsb[(size_t)src * 16 + ((dst & 511) >> 5)], 1u << (dst & 31));
    }
    r13_bar(cnt, 1);

    // ---------------- P2: bitset -> CSR planes ----------------
    if (gtid < 2 * NNt) {
        const int node = gtid & 8191;
        const uint32_t* bs = (gtid < NNt) ? (fwdb + (size_t)node * 16)
                                          : (trsb + (size_t)node * 16);
        unsigned short* cs = (gtid < NNt) ? csrF : csrT;
        int c2 = 0;
        for (int w = 0; w < 16; ++w) {
            uint32_t bits = bs[w];
            while (bits) {
                const int u = (w << 5) + __ffs(bits) - 1;
                bits &= bits - 1;
                if (c2 < MAXD) cs[(size_t)c2 * 8192 + node] = (unsigned short)u;
                ++c2;
            }
        }
        for (int j = c2; j < MAXD; ++j) cs[(size_t)j * 8192 + node] = PADR;
    }
    r13_bar(cnt, 2);

    // ---------------- P3: deg chain (blocks 0..15) ----------------
    if (B < BB) {
        float* pa = smf; float* pb = smf + 513; float* wsh = smf + 1026;
        const int node = B * 512 + t;
        int iF[MAXD];
#pragma unroll
        for (int j = 0; j < MAXD; ++j) iF[j] = (int)csrF[(size_t)j * 8192 + node];
        if (t < 21) wsh[t] = panw[t];
        pa[t] = 1.0f;
        if (t == 0) { pa[512] = 0.0f; pb[512] = 0.0f; }
        __syncthreads();
        float dacc = wsh[0];
        float* rp = pa; float* rn = pb;
        for (int i = 1; i <= LLp; ++i) {
            float tv[MAXD];
#pragma unroll
            for (int j = 0; j < MAXD; ++j) tv[j] = rp[iF[j]];
            float s = 0.0f;
#pragma unroll
            for (int j = 0; j < MAXD; ++j) s += tv[j];
            rn[t] = s;
            dacc += wsh[i] * s;
            __syncthreads();
            float* tp = rp; rp = rn; rn = tp;
        }
        disv[node] = (dacc > 0.0f) ? 1.0f / sqrtf(dacc) : 0.0f;
    }
    r13_bar(cnt, 3);

    // ---------------- P4: chan (blocks 0..63) then closure (all blocks) ----
    if (B < 64) {                                   // one scalar chain per (graph, c)
        float* pa = smf; float* pb = smf + 513; float* wsh = smf + 1026;
        const int b = B >> 2, c = B & 3;
        const int node = b * 512 + t;
        const unsigned short* csr = (c < 3) ? csrF : csrT;
        int idx[MAXD];
#pragma unroll
        for (int j = 0; j < MAXD; ++j) idx[j] = (int)csr[(size_t)j * 8192 + node];
        if (t < 21) wsh[t] = panw[t];
        const float d0 = disv[node];
        float seed;
        if (c < 3) {
            float xw = 0.0f;
            const float* xr = x + (size_t)node * NFf;
            for (int f = 0; f < NFf; ++f) xw += xr[f] * l1w[f * 3 + c];
            seed = d0 * xw;
        } else {
            seed = d0;
        }
        pa[t] = seed;
        if (t == 0) { pa[512] = 0.0f; pb[512] = 0.0f; }
        __syncthreads();
        float acc = wsh[0] * seed;
        float* rp = pa; float* rn = pb;
        for (int i = 1; i <= LLp; ++i) {
            float tv[MAXD];
#pragma unroll
            for (int j = 0; j < MAXD; ++j) tv[j] = rp[idx[j]];
            float s = 0.0f;
#pragma unroll
            for (int j = 0; j < MAXD; ++j) s += tv[j];
            rn[t] = s;
            acc += wsh[i] * s;
            __syncthreads();
            float* tp = rp; rp = rn; rn = tp;
        }
        if (c < 3) h_raw[(size_t)node * 3 + c] = r13_sane(d0 * acc + l1b[c]);
        else       colsum[node] = r13_sane(d0 * acc);
        __syncthreads();                            // LDS dead before closure reuse
    }
    {                                               // closure: 256 windows over 256 blocks
        const int w = (B < 64) ? (192 + B) : (B - 64);
        const int b = w >> 4, q = w & 15;
        uint32_t* R1 = (uint32_t*)smf;
        uint32_t* R2 = (uint32_t*)(smf + 513);
        const int node = b * 512 + t;
        int iF[MAXD];
#pragma unroll
        for (int j = 0; j < MAXD; ++j) iF[j] = (int)csrF[(size_t)j * 8192 + node];
        R1[t] = ((t >> 5) == q) ? (1u << (t & 31)) : 0u;
        if (t == 0) { R1[512] = 0u; R2[512] = 0u; }
        __syncthreads();
        uint32_t* Rp = R1; uint32_t* Rn = R2;
        for (int i = 0; i < LLp; ++i) {
            uint32_t tv[MAXD];
#pragma unroll
            for (int j = 0; j < MAXD; ++j) tv[j] = Rp[iF[j]];
            uint32_t r = Rp[t];
#pragma unroll
            for (int j = 0; j < MAXD; ++j) r |= tv[j];
            Rn[t] = r;
            __syncthreads();
            uint32_t* tp = Rp; Rp = Rn; Rn = tp;
        }
        Rb[(size_t)node * 16 + q] = Rp[t];
    }
    r13_bar(cnt, 4);

    // ---------------- P5: pool (blocks 0..15) ----------------
    if (B < BB) {
        float* red = smf; float* sc = smf + 512; float* mv = smf + 1024;
        const int b = B, v = t;
        const float inv_n = 1.0f / (float)NNt;
        float hv0[16], hv1[16], hv2[16];
        float s0 = 0.0f, s1 = 0.0f, s2 = 0.0f;
#pragma unroll
        for (int k = 0; k < 16; ++k) {
            const float* hr = h_raw + (size_t)(k * 512 + v) * 3;
            hv0[k] = hr[0]; hv1[k] = hr[1]; hv2[k] = hr[2];
            s0 += hv0[k]; s1 += hv1[k]; s2 += hv2[k];
        }
        float acc[3] = { s0, s1, s2 };
        for (int c = 0; c < 3; ++c) {
            __syncthreads();
            red[v] = acc[c];
            __syncthreads();
            for (int st = 256; st > 0; st >>= 1) {
                if (v < st) red[v] += red[v + st];
                __syncthreads();
            }
            if (v == 0) mv[c] = red[0] * inv_n;
        }
        __syncthreads();
        const float mm0 = n1ms[0] * mv[0], mm1 = n1ms[1] * mv[1], mm2 = n1ms[2] * mv[2];
        float a0 = 0.0f, a1 = 0.0f, a2 = 0.0f;
#pragma unroll
        for (int k = 0; k < 16; ++k) {
            const float d0 = hv0[k] - mm0, d1 = hv1[k] - mm1, d2 = hv2[k] - mm2;
            a0 += d0 * d0; a1 += d1 * d1; a2 += d2 * d2;
        }
        float accv[3] = { a0, a1, a2 };
        for (int c = 0; c < 3; ++c) {
            __syncthreads();
            red[v] = accv[c];
            __syncthreads();
            for (int st = 256; st > 0; st >>= 1) {
                if (v < st) red[v] += red[v + st];
                __syncthreads();
            }
            if (v == 0) mv[3 + c] = red[0] * inv_n;
        }
        __syncthreads();
        const float mmv[3] = { mm0, mm1, mm2 };
        float xv[3];
#pragma unroll
        for (int c = 0; c < 3; ++c) {
            const float iv = 1.0f / sqrtf(fmaxf(mv[3 + c], 0.0f) + EPSf);
            const float o  = h_raw[(size_t)(b * NPn + v) * 3 + c] - mmv[c];
            const float tt = n1w[c] * o * iv + n1b[c];
            xv[c] = fmaxf(tt, 0.0f);
            x1[(size_t)(b * NPn + v) * 3 + c] = xv[c];
        }
        float s = poolb[0] * (xv[0] * poolp[0] + xv[1] * poolp[1] + xv[2] * poolp[2])
                + poolb[1] * colsum[b * NPn + v];
        s = tanhf(s);
        if (!(s == s)) s = 0.0f;
        sc[v] = s;
        __syncthreads();
        int c3 = 0;
        for (int u = 0; u < NPn; ++u) {
            const float su = sc[u];
            c3 += ((su > s) || (su == s && u < v)) ? 1 : 0;   // lax.top_k tie-break
        }
        if (c3 < KKk) {
            kept[b * KPAD + c3] = v;
            xp[(size_t)(b * KPAD + c3) * 3 + 0] = xv[0] * s;
            xp[(size_t)(b * KPAD + c3) * 3 + 1] = xv[1] * s;
            xp[(size_t)(b * KPAD + c3) * 3 + 2] = xv[2] * s;
        }
    }
    r13_bar(cnt, 5);

    // ---------------- P6: GAT (blocks 0..63), wave-per-row online softmax ----
    if (B < 64) {
        float* xlS = smf;                               // 1230 floats
        int* kidx = (int*)(smf + 1232);                 // 416 ints
        uint32_t* RT = (uint32_t*)(smf + 1648);         // 16*416 words
        const int b = B >> 2;
        const int lane = t & 63, wv = t >> 6;
        const int wid = (B & 3) * 8 + wv;               // 0..31
        float Wl[9], Wr[9];
#pragma unroll
        for (int i2 = 0; i2 < 9; ++i2) { Wl[i2] = gwl[i2]; Wr[i2] = gwr[i2]; }
        const float Bl0 = gbl[0], Bl1 = gbl[1], Bl2 = gbl[2];
        const float Br0 = gbr[0], Br1 = gbr[1], Br2 = gbr[2];
        const float At0 = gatt[0], At1 = gatt[1], At2 = gatt[2];
        const float Gb0 = gbias[0], Gb1 = gbias[1], Gb2 = gbias[2];

        for (int j = t; j < KKk; j += 512) {
            const int vj = kept[b * KPAD + j];
            kidx[j] = vj;
            const float p0 = xp[(size_t)(b * KPAD + j) * 3 + 0];
            const float p1 = xp[(size_t)(b * KPAD + j) * 3 + 1];
            const float p2 = xp[(size_t)(b * KPAD + j) * 3 + 2];
            xlS[j * 3 + 0] = p0 * Wl[0] + p1 * Wl[3] + p2 * Wl[6] + Bl0;
            xlS[j * 3 + 1] = p0 * Wl[1] + p1 * Wl[4] + p2 * Wl[7] + Bl1;
            xlS[j * 3 + 2] = p0 * Wl[2] + p1 * Wl[5] + p2 * Wl[8] + Bl2;
            const uint32_t* rr = Rb + (size_t)(b * NPn + vj) * 16;
#pragma unroll
            for (int w = 0; w < 16; ++w) RT[w * KPAD + j] = rr[w];
        }
        __syncthreads();

        for (int i = wid; i < KKk; i += 32) {
            const float p0 = xp[(size_t)(b * KPAD + i) * 3 + 0];
            const float p1 = xp[(size_t)(b * KPAD + i) * 3 + 1];
            const float p2 = xp[(size_t)(b * KPAD + i) * 3 + 2];
            const float xr0 = p0 * Wr[0] + p1 * Wr[3] + p2 * Wr[6] + Br0;
            const float xr1 = p0 * Wr[1] + p1 * Wr[4] + p2 * Wr[7] + Br1;
            const float xr2 = p0 * Wr[2] + p1 * Wr[5] + p2 * Wr[8] + Br2;
            const int bi = kidx[i];
            const uint32_t mbit = 1u << (bi & 31);
            const uint32_t* Rw = &RT[(bi >> 5) * KPAD];
            float mx = -3e38f, lsum = 0.0f, a0 = 0.0f, a1 = 0.0f, a2 = 0.0f;
            for (int j = lane; j < KKk; j += 64) {
                if ((Rw[j] & mbit) || (j == i)) {
                    float e0 = xr0 + xlS[j * 3 + 0]; e0 = e0 > 0.0f ? e0 : 0.2f * e0;
                    float e1 = xr1 + xlS[j * 3 + 1]; e1 = e1 > 0.0f ? e1 : 0.2f * e1;
                    float e2 = xr2 + xlS[j * 3 + 2]; e2 = e2 > 0.0f ? e2 : 0.2f * e2;
                    const float s = At0 * e0 + At1 * e1 + At2 * e2;
                    if (s > mx) {
                        const float r = __expf(mx - s);
                        lsum *= r; a0 *= r; a1 *= r; a2 *= r;
                        mx = s;
                    }
                    const float pj = __expf(s - mx);
                    lsum += pj;
                    a0 += pj * xlS[j * 3 + 0];
                    a1 += pj * xlS[j * 3 + 1];
                    a2 += pj * xlS[j * 3 + 2];
                }
            }
            for (int off = 32; off; off >>= 1) {        // butterfly LSE merge
                const float mo = __shfl_xor(mx, off);
                const float lo = __shfl_xor(lsum, off);
                const float b0 = __shfl_xor(a0, off);
                const float b1 = __shfl_xor(a1, off);
                const float b2 = __shfl_xor(a2, off);
                const float M  = fmaxf(mx, mo);
                const float ea = __expf(mx - M), eb = __expf(mo - M);
                lsum = lsum * ea + lo * eb;
                a0 = a0 * ea + b0 * eb;
                a1 = a1 * ea + b1 * eb;
                a2 = a2 * ea + b2 * eb;
                mx = M;
            }
            if (lane == 0) {
                const float rl = 1.0f / fmaxf(lsum, 1e-30f);
                g_raw[(size_t)(b * KPAD + i) * 3 + 0] = r13_sane(a0 * rl + Gb0);
                g_raw[(size_t)(b * KPAD + i) * 3 + 1] = r13_sane(a1 * rl + Gb1);
                g_raw[(size_t)(b * KPAD + i) * 3 + 2] = r13_sane(a2 * rl + Gb2);
            }
        }
    }
    r13_bar(cnt, 6);

    // ---------------- P7: head (blocks 0..15) ----------------
    if (B < BB) {
        float* rbuf = smf;                              // 512
        float* mv   = smf + 512;                        // 6
        float* gp   = smf + 520;                        // 3
        float* feat = smf + 524;                        // 19
        float* h1a  = smf + 544;                        // 10
        float* h1v  = smf + 554;                        // 10
        float* h2a  = smf + 564;                        // 5
        float* h2v  = smf + 569;                        // 5
        float* a3   = smf + 574;                        // 50
        float* vout = smf + 624;
        float* amean = smf + 625;
        const int b = B;
        const float denom = 1.0f / (float)(BB * KKk);

        float gv0[13], gv1[13], gv2[13];
        float s0 = 0.0f, s1 = 0.0f, s2 = 0.0f;
#pragma unroll
        for (int k = 0; k < 13; ++k) {
            const int r = k * 512 + t;
            float q0 = 0.0f, q1 = 0.0f, q2 = 0.0f;
            if (r < BB * KKk) {
                const int bq = r / KKk, iq = r - bq * KKk;
                const float* gr = g_raw + (size_t)(bq * KPAD + iq) * 3;
                q0 = gr[0]; q1 = gr[1]; q2 = gr[2];
            }
            gv0[k] = q0; gv1[k] = q1; gv2[k] = q2;
            s0 += q0; s1 += q1; s2 += q2;
        }
        float acc[3] = { s0, s1, s2 };
        for (int c = 0; c < 3; ++c) {
            __syncthreads();
            rbuf[t] = acc[c];
            __syncthreads();
            for (int st = 256; st > 0; st >>= 1) {
                if (t < st) rbuf[t] += rbuf[t + st];
                __syncthreads();
            }
            if (t == 0) mv[c] = rbuf[0] * denom;
        }
        __syncthreads();
        const float mm0 = n2ms[0] * mv[0], mm1 = n2ms[1] * mv[1], mm2 = n2ms[2] * mv[2];
        float a0 = 0.0f, a1 = 0.0f, a2 = 0.0f;
#pragma unroll
        for (int k = 0; k < 13; ++k) {
            const int r = k * 512 + t;
            if (r < BB * KKk) {
                const float d0 = gv0[k] - mm0, d1 = gv1[k] - mm1, d2 = gv2[k] - mm2;
                a0 += d0 * d0; a1 += d1 * d1; a2 += d2 * d2;
            }
        }
        float accv[3] = { a0, a1, a2 };
        for (int c = 0; c < 3; ++c) {
            __syncthreads();
            rbuf[t] = accv[c];
            __syncthreads();
            for (int st = 256; st > 0; st >>= 1) {
                if (t < st) rbuf[t] += rbuf[t + st];
                __syncthreads();
            }
            if (t == 0) mv[3 + c] = rbuf[0] * denom;
        }
        __syncthreads();
        const float mmv[3] = { mm0, mm1, mm2 };
        float s3[3] = { 0.0f, 0.0f, 0.0f };
        if (t < KKk) {
            const size_t r = (size_t)(b * KPAD + t) * 3;
#pragma unroll
            for (int c = 0; c < 3; ++c) {
                const float iv = 1.0f / sqrtf(fmaxf(mv[3 + c], 0.0f) + EPSf);
                s3[c] = fmaxf((g_raw[r + c] - mmv[c]) * iv * n2w[c] + n2b[c], 0.0f);
            }
        }
        for (int c = 0; c < 3; ++c) {
            __syncthreads();
            rbuf[t] = s3[c];
            __syncthreads();
            for (int st = 256; st > 0; st >>= 1) {
                if (t < st) rbuf[t] += rbuf[t + st];
                __syncthreads();
            }
            if (t == 0) gp[c] = rbuf[0];
        }
        __syncthreads();

        if (t < 19) {
            const int gidx = cnid[b] + b * KKk;        // faithful: pooled-K offsets
            float fv;
            if (t < 13)      fv = x[(size_t)gidx * NFf + t];
            else if (t < 16) fv = x1[(size_t)gidx * 3 + (t - 13)];
            else             fv = gp[t - 16];
            feat[t] = fv;
        }
        __syncthreads();

        if (t < 10) {
            float s = a1b[t];
            for (int f = 0; f < 19; ++f) s += feat[f] * a1w[f * 10 + t];
            h1a[t] = fmaxf(s, 0.0f);
        } else if (t >= 64 && t < 74) {
            const int j = t - 64;
            float s = v1b[j];
            for (int f = 0; f < 19; ++f) s += feat[f] * v1w[f * 10 + j];
            h1v[j] = fmaxf(s, 0.0f);
        }
        __syncthreads();
        if (t < 5) {
            float s = a2b[t];
            for (int k = 0; k < 10; ++k) s += h1a[k] * a2w[k * 5 + t];
            h2a[t] = fmaxf(s, 0.0f);
        } else if (t >= 64 && t < 69) {
            const int j = t - 64;
            float s = v2b[j];
            for (int k = 0; k < 10; ++k) s += h1v[k] * v2w[k * 5 + j];
            h2v[j] = fmaxf(s, 0.0f);
        }
        __syncthreads();
        if (t < 50) {
            float s = a3b[t];
            for (int k = 0; k < 5; ++k) s += h2a[k] * a3w[k * 50 + t];
            a3[t] = s;
        } else if (t == 64) {
            float s = v3b[0];
            for (int k = 0; k < 5; ++k) s += h2v[k] * v3w[k];
            *vout = s;
        }
        __syncthreads();
        if (t == 0) {
            float s = 0.0f;
            for (int k = 0; k < 50; ++k) s += a3[k];
            *amean = s * (1.0f / 50.0f);
        }
        __syncthreads();
        if (t < 50) {
            float q = *vout + a3[t] - *amean;
            if (!(q == q)) q = 0.0f;
            q = fminf(fmaxf(q, -QCLMP), QCLMP);
            out[b * NAa + t] = (amask[b * NAa + t] == 0) ? -1e8f : q;   // FP32
        }
    }
}

// ---------------------------------------------------------------------------
extern "C" void kernel_launch(void* const* d_in, const int* in_sizes, int n_in,
                              void* d_out, int out_size, void* d_ws, size_t ws_size,
                              hipStream_t stream) {
    (void)in_sizes; (void)n_in; (void)out_size;
    const float* x     = (const float*)d_in[0];
    const int* ei      = (const int*)d_in[1];
    const int* cnid    = (const int*)d_in[4];
    const int* amask   = (const int*)d_in[5];
    const float* panw  = (const float*)d_in[6];
    const float* l1w   = (const float*)d_in[7];
    const float* l1b   = (const float*)d_in[8];
    const float* n1w   = (const float*)d_in[9];
    const float* n1b   = (const float*)d_in[10];
    const float* n1ms  = (const float*)d_in[11];
    const float* poolp = (const float*)d_in[12];
    const float* poolb = (const float*)d_in[13];
    const float* gwl   = (const float*)d_in[14];
    const float* gbl   = (const float*)d_in[15];
    const float* gwr   = (const float*)d_in[16];
    const float* gbr   = (const float*)d_in[17];
    const float* gatt  = (const float*)d_in[18];
    const float* gbias = (const float*)d_in[19];
    const float* n2w   = (const float*)d_in[20];
    const float* n2b   = (const float*)d_in[21];
    const float* n2ms  = (const float*)d_in[22];
    const float* v1w   = (const float*)d_in[23];
    const float* v1b   = (const float*)d_in[24];
    const float* v2w   = (const float*)d_in[25];
    const float* v2b   = (const float*)d_in[26];
    const float* v3w   = (const float*)d_in[27];
    const float* v3b   = (const float*)d_in[28];
    const float* a1w   = (const float*)d_in[29];
    const float* a1b   = (const float*)d_in[30];
    const float* a2w   = (const float*)d_in[31];
    const float* a2b   = (const float*)d_in[32];
    const float* a3w   = (const float*)d_in[33];
    const float* a3b   = (const float*)d_in[34];
    float* out         = (float*)d_out;

    // ws layout (bytes):
    //   [0,512K)        fwd bitset
    //   [512K,1M)       trs bitset (aliased as Rb after extract)
    //   [1M,1M+256)     barrier counter (zeroed by memset below)
    //   then csrF, csrT (u16 planes), then float buffers
    uint8_t* wsb = (uint8_t*)d_ws;
    uint32_t* fwdb = (uint32_t*)wsb;
    uint32_t* trsb = (uint32_t*)(wsb + 524288);
    uint32_t* cnt  = (uint32_t*)(wsb + 1048576);
    unsigned short* csrF = (unsigned short*)(wsb + 1048576 + 256);
    unsigned short* csrT = csrF + (size_t)MAXD * 8192;
    float* h_raw  = (float*)(csrT + (size_t)MAXD * 8192);
    float* x1     = h_raw + (size_t)NNt * 3;
    float* colsum = x1 + (size_t)NNt * 3;
    float* disv   = colsum + NNt;
    float* xp     = disv + NNt;
    float* g_raw  = xp + (size_t)BB * KPAD * 3;
    int*   kept   = (int*)(g_raw + (size_t)BB * KPAD * 3);
    const size_t needed = 1048576 + 256 + 2 * (size_t)MAXD * 8192 * 2 +
                          ((size_t)(2 * NNt * 3 + 2 * NNt + 2 * BB * KPAD * 3 + BB * KPAD)) * 4;
    if (ws_size < needed) return;

    hipMemsetAsync(fwdb, 0, 1048576 + 256, stream);   // bitsets + barrier counter
    r13_mega<<<dim3(NBLK), dim3(512), 0, stream>>>(
        x, ei, cnid, amask, panw, l1w, l1b, n1w, n1b, n1ms, poolp, poolb,
        gwl, gbl, gwr, gbr, gatt, gbias, n2w, n2b, n2ms,
        v1w, v1b, v2w, v2b, v3w, v3b, a1w, a1b, a2w, a2b, a3w, a3b,
        fwdb, trsb, cnt, csrF, csrT, h_raw, x1, colsum, disv, xp, g_raw, kept, out);
}

// Round 14
// 344.288 us; speedup vs baseline: 1.8328x; 1.8328x over previous
//
#include <hip/hip_runtime.h>
#include <hip/hip_bf16.h>
#include <stdint.h>
#include <math.h>

// PANConcDQL round 14 -- math identical to round 12 (passed, absmax 0.0).
// Lesson from r13: grid barriers => L2 writeback storm on multi-XCD; reverted.
// Changes vs r12: 5 dispatches (memset, scatter, mid = chan||closure with
// in-register bitset extraction, poolgat fused with LDS-resident kept/xp,
// head); degree-tiered (16/28) unrolled chain gathers.
#define BB   16
#define NPn  512
#define LLp  20
#define NAa  50
#define KKk  410
#define NNt  (BB * NPn)   // 8192
#define EEe  (6 * NNt)    // 49152
#define NFf  13
#define KPAD 416
#define EPSf 1e-5f
#define QCLMP 1e6f
#define MAXD 28
#define PADR 512

__device__ __forceinline__ float r14_sane(float v) {
    if (!(v == v)) return 0.0f;
    return fminf(fmaxf(v, -1e15f), 1e15f);
}

// extract up to MAXD neighbor indices from a 16-word bitset row; pad with PADR
__device__ __forceinline__ int r14_extract(const uint32_t* __restrict__ bs, int* idx) {
    int cnt = 0;
    for (int w = 0; w < 16; ++w) {
        uint32_t bits = bs[w];
        while (bits) {
            const int u = (w << 5) + __ffs(bits) - 1;
            bits &= bits - 1;
            if (cnt < MAXD) idx[cnt] = u;
            ++cnt;
        }
    }
    const int c = (cnt < MAXD) ? cnt : MAXD;
    for (int j = c; j < MAXD; ++j) idx[j] = PADR;
    return c;
}

// 20-step scalar chain in LDS; N-wide unrolled gathers (pad slot 512 = 0).
template<int N>
__device__ __forceinline__ float r14_chain(float* RA, float* RB, const int* idx,
                                           const float* wsh, int v, float seed) {
    RA[v] = seed;
    if (v == 0) { RA[512] = 0.0f; RB[512] = 0.0f; }
    __syncthreads();
    float acc = wsh[0] * seed;
    float* rp = RA; float* rn = RB;
    for (int i = 1; i <= LLp; ++i) {
        float tv[N];
#pragma unroll
        for (int j = 0; j < N; ++j) tv[j] = rp[idx[j]];
        float s = 0.0f;
#pragma unroll
        for (int j = 0; j < N; ++j) s += tv[j];
        rn[v] = s;
        acc += wsh[i] * s;
        __syncthreads();
        float* tp = rp; rp = rn; rn = tp;
    }
    return acc;
}

template<int N>
__device__ __forceinline__ void r14_cchain(uint32_t* R1, uint32_t* R2, const int* idx,
                                           int v, int q, uint32_t* __restrict__ Rb, int node) {
    R1[v] = ((v >> 5) == q) ? (1u << (v & 31)) : 0u;
    if (v == 0) { R1[512] = 0u; R2[512] = 0u; }
    __syncthreads();
    uint32_t* Rp = R1; uint32_t* Rn = R2;
    for (int i = 0; i < LLp; ++i) {
        uint32_t tv[N];
#pragma unroll
        for (int j = 0; j < N; ++j) tv[j] = Rp[idx[j]];
        uint32_t r = Rp[v];
#pragma unroll
        for (int j = 0; j < N; ++j) r |= tv[j];
        Rn[v] = r;
        __syncthreads();
        uint32_t* tp = Rp; Rp = Rn; Rn = tp;
    }
    Rb[(size_t)node * 16 + q] = Rp[v];
}

// ---------------------------------------------------------------------------
// K1: edge scatter -> global bitsets.
__global__ __launch_bounds__(256) void r14_scatter(
    const int* __restrict__ ei,
    uint32_t* __restrict__ fwdb, uint32_t* __restrict__ trsb)
{
    const int e = blockIdx.x * 256 + threadIdx.x;
    if (e < EEe) {
        const int src = ei[e], dst = ei[EEe + e];
        atomicOr(&fwdb[(size_t)dst * 16 + ((src & 511) >> 5)], 1u << (src & 31));
        atomicOr(&trsb[(size_t)src * 16 + ((dst & 511) >> 5)], 1u << (dst & 31));
    }
}

// ---------------------------------------------------------------------------
// K2: mid, grid (16,20) x 512.
//  y<4: deg chain (over fwd) then channel chain: c<3 Y-channel (fwd),
//       c=3 z-chain (trs). In-register extraction from bitsets.
//  y>=4: closure window q = y-4 (fwd).
__global__ __launch_bounds__(512) void r14_mid(
    const float* __restrict__ x,
    const uint32_t* __restrict__ fwdb,
    const uint32_t* __restrict__ trsb,
    const float* __restrict__ panw,
    const float* __restrict__ l1w, const float* __restrict__ l1b,
    float* __restrict__ h_raw, float* __restrict__ colsum,
    uint32_t* __restrict__ Rb)
{
    __shared__ __align__(16) uint32_t sbuf[1056];
    float* pa = (float*)sbuf;              // 513
    float* pb = (float*)(sbuf + 513);      // 513
    float* wsh = (float*)(sbuf + 1026);    // 21
    int* mxS = (int*)(sbuf + 1048);        // 2
    const int b = blockIdx.x, y = blockIdx.y, t = threadIdx.x;
    const int node = b * 512 + t;

    if (y < 4) {
        const int c = y;
        int iF[MAXD], iT[MAXD];
        const int cntF = r14_extract(fwdb + (size_t)node * 16, iF);
        int cntT = 0;
        if (c == 3) cntT = r14_extract(trsb + (size_t)node * 16, iT);
        if (t == 0) { mxS[0] = 0; mxS[1] = 0; }
        if (t < 21) wsh[t] = panw[t];
        __syncthreads();
        atomicMax(&mxS[0], cntF);
        if (c == 3) atomicMax(&mxS[1], cntT);
        __syncthreads();
        const int mF = mxS[0], mT = mxS[1];

        // deg chain over fwd indices
        float dacc;
        if (mF <= 16) dacc = r14_chain<16>(pa, pb, iF, wsh, t, 1.0f);
        else          dacc = r14_chain<28>(pa, pb, iF, wsh, t, 1.0f);
        const float d0 = (dacc > 0.0f) ? 1.0f / sqrtf(dacc) : 0.0f;

        if (c < 3) {
            float xw = 0.0f;
            const float* xr = x + (size_t)node * NFf;
            for (int f = 0; f < NFf; ++f) xw += xr[f] * l1w[f * 3 + c];
            float acc;
            if (mF <= 16) acc = r14_chain<16>(pa, pb, iF, wsh, t, d0 * xw);
            else          acc = r14_chain<28>(pa, pb, iF, wsh, t, d0 * xw);
            h_raw[(size_t)node * 3 + c] = r14_sane(d0 * acc + l1b[c]);
        } else {
            float acc;
            if (mT <= 16) acc = r14_chain<16>(pa, pb, iT, wsh, t, d0);
            else          acc = r14_chain<28>(pa, pb, iT, wsh, t, d0);
            colsum[node] = r14_sane(d0 * acc);
        }
    } else {
        const int q = y - 4;
        int iF[MAXD];
        const int cntF = r14_extract(fwdb + (size_t)node * 16, iF);
        if (t == 0) mxS[0] = 0;
        __syncthreads();
        atomicMax(&mxS[0], cntF);
        __syncthreads();
        const int mF = mxS[0];
        uint32_t* R1 = sbuf;
        uint32_t* R2 = sbuf + 513;
        if (mF <= 16) r14_cchain<16>(R1, R2, iF, t, q, Rb, node);
        else          r14_cchain<28>(R1, R2, iF, t, q, Rb, node);
    }
}

// ---------------------------------------------------------------------------
// K3: poolgat, grid 16 x 512. Pool (GraphNorm1 two-pass, PANPool score,
// stable top-K) with kept/xp in LDS, then GAT (wave-per-row online softmax).
__global__ __launch_bounds__(512) void r14_poolgat(
    const float* __restrict__ h_raw,
    const float* __restrict__ colsum,
    const uint32_t* __restrict__ Rb,
    const float* n1w, const float* n1b, const float* n1ms,
    const float* poolp, const float* poolb,
    const float* gwl, const float* gbl,
    const float* gwr, const float* gbr,
    const float* gatt, const float* gbias,
    float* __restrict__ x1,
    float* __restrict__ g_raw)
{
    __shared__ __align__(16) uint32_t pg[10592];
    float* red  = (float*)pg;                  // 512
    float* sc   = (float*)(pg + 512);          // 512
    float* mv   = (float*)(pg + 1024);         // 8
    float* xpS  = (float*)(pg + 1032);         // 1248 (416*3)
    int*   kidx = (int*)(pg + 2280);           // 416
    float* xlS  = (float*)(pg + 2696);         // 1232
    uint32_t* RT = pg + 3928;                  // 16*416 = 6656
    const int b = blockIdx.x, t = threadIdx.x;
    const float inv_n = 1.0f / (float)NNt;

    // ---- pool: norm1 stats (two-pass over all graphs) ----
    float hv0[16], hv1[16], hv2[16];
    float s0 = 0.0f, s1 = 0.0f, s2 = 0.0f;
#pragma unroll
    for (int k = 0; k < 16; ++k) {
        const float* hr = h_raw + (size_t)(k * 512 + t) * 3;
        hv0[k] = hr[0]; hv1[k] = hr[1]; hv2[k] = hr[2];
        s0 += hv0[k]; s1 += hv1[k]; s2 += hv2[k];
    }
    float acc[3] = { s0, s1, s2 };
    for (int c = 0; c < 3; ++c) {
        __syncthreads();
        red[t] = acc[c];
        __syncthreads();
        for (int st = 256; st > 0; st >>= 1) {
            if (t < st) red[t] += red[t + st];
            __syncthreads();
        }
        if (t == 0) mv[c] = red[0] * inv_n;
    }
    __syncthreads();
    const float mm0 = n1ms[0] * mv[0], mm1 = n1ms[1] * mv[1], mm2 = n1ms[2] * mv[2];
    float a0 = 0.0f, a1 = 0.0f, a2 = 0.0f;
#pragma unroll
    for (int k = 0; k < 16; ++k) {
        const float d0 = hv0[k] - mm0, d1 = hv1[k] - mm1, d2 = hv2[k] - mm2;
        a0 += d0 * d0; a1 += d1 * d1; a2 += d2 * d2;
    }
    float accv[3] = { a0, a1, a2 };
    for (int c = 0; c < 3; ++c) {
        __syncthreads();
        red[t] = accv[c];
        __syncthreads();
        for (int st = 256; st > 0; st >>= 1) {
            if (t < st) red[t] += red[t + st];
            __syncthreads();
        }
        if (t == 0) mv[3 + c] = red[0] * inv_n;
    }
    __syncthreads();

    const float mmv[3] = { mm0, mm1, mm2 };
    float xv[3];
#pragma unroll
    for (int c = 0; c < 3; ++c) {
        const float iv = 1.0f / sqrtf(fmaxf(mv[3 + c], 0.0f) + EPSf);
        const float o  = h_raw[(size_t)(b * NPn + t) * 3 + c] - mmv[c];
        const float tt = n1w[c] * o * iv + n1b[c];
        xv[c] = fmaxf(tt, 0.0f);
        x1[(size_t)(b * NPn + t) * 3 + c] = xv[c];
    }
    float s = poolb[0] * (xv[0] * poolp[0] + xv[1] * poolp[1] + xv[2] * poolp[2])
            + poolb[1] * colsum[b * NPn + t];
    s = tanhf(s);
    if (!(s == s)) s = 0.0f;
    sc[t] = s;
    __syncthreads();
    int cnt = 0;
    for (int u = 0; u < NPn; ++u) {
        const float su = sc[u];
        cnt += ((su > s) || (su == s && u < t)) ? 1 : 0;   // lax.top_k tie-break
    }
    if (cnt < KKk) {                       // rank-count is a bijection: each slot once
        kidx[cnt] = t;
        xpS[cnt * 3 + 0] = xv[0] * s;
        xpS[cnt * 3 + 1] = xv[1] * s;
        xpS[cnt * 3 + 2] = xv[2] * s;
    }
    __syncthreads();

    // ---- GAT staging: xl = xp@Wl+bl; RT transposed mask words ----
    float Wl[9], Wr[9];
#pragma unroll
    for (int i2 = 0; i2 < 9; ++i2) { Wl[i2] = gwl[i2]; Wr[i2] = gwr[i2]; }
    const float Bl0 = gbl[0], Bl1 = gbl[1], Bl2 = gbl[2];
    const float Br0 = gbr[0], Br1 = gbr[1], Br2 = gbr[2];
    const float At0 = gatt[0], At1 = gatt[1], At2 = gatt[2];
    const float Gb0 = gbias[0], Gb1 = gbias[1], Gb2 = gbias[2];
    for (int j = t; j < KKk; j += 512) {
        const float p0 = xpS[j * 3 + 0];
        const float p1 = xpS[j * 3 + 1];
        const float p2 = xpS[j * 3 + 2];
        xlS[j * 3 + 0] = p0 * Wl[0] + p1 * Wl[3] + p2 * Wl[6] + Bl0;
        xlS[j * 3 + 1] = p0 * Wl[1] + p1 * Wl[4] + p2 * Wl[7] + Bl1;
        xlS[j * 3 + 2] = p0 * Wl[2] + p1 * Wl[5] + p2 * Wl[8] + Bl2;
        const uint32_t* rr = Rb + (size_t)(b * NPn + kidx[j]) * 16;
#pragma unroll
        for (int w = 0; w < 16; ++w) RT[w * KPAD + j] = rr[w];
    }
    __syncthreads();

    // ---- GAT rows: wave wv handles i = wv, wv+8, ... ----
    const int lane = t & 63, wv = t >> 6;
    for (int i = wv; i < KKk; i += 8) {
        const float p0 = xpS[i * 3 + 0];
        const float p1 = xpS[i * 3 + 1];
        const float p2 = xpS[i * 3 + 2];
        const float xr0 = p0 * Wr[0] + p1 * Wr[3] + p2 * Wr[6] + Br0;
        const float xr1 = p0 * Wr[1] + p1 * Wr[4] + p2 * Wr[7] + Br1;
        const float xr2 = p0 * Wr[2] + p1 * Wr[5] + p2 * Wr[8] + Br2;
        const int bi = kidx[i];
        const uint32_t mbit = 1u << (bi & 31);
        const uint32_t* Rw = &RT[(bi >> 5) * KPAD];
        float mx = -3e38f, lsum = 0.0f, b0 = 0.0f, b1 = 0.0f, b2 = 0.0f;
        for (int j = lane; j < KKk; j += 64) {
            if ((Rw[j] & mbit) || (j == i)) {
                float e0 = xr0 + xlS[j * 3 + 0]; e0 = e0 > 0.0f ? e0 : 0.2f * e0;
                float e1 = xr1 + xlS[j * 3 + 1]; e1 = e1 > 0.0f ? e1 : 0.2f * e1;
                float e2 = xr2 + xlS[j * 3 + 2]; e2 = e2 > 0.0f ? e2 : 0.2f * e2;
                const float sv = At0 * e0 + At1 * e1 + At2 * e2;
                if (sv > mx) {
                    const float r = __expf(mx - sv);
                    lsum *= r; b0 *= r; b1 *= r; b2 *= r;
                    mx = sv;
                }
                const float pj = __expf(sv - mx);
                lsum += pj;
                b0 += pj * xlS[j * 3 + 0];
                b1 += pj * xlS[j * 3 + 1];
                b2 += pj * xlS[j * 3 + 2];
            }
        }
        for (int off = 32; off; off >>= 1) {       // butterfly LSE merge
            const float mo = __shfl_xor(mx, off);
            const float lo = __shfl_xor(lsum, off);
            const float c0 = __shfl_xor(b0, off);
            const float c1 = __shfl_xor(b1, off);
            const float c2 = __shfl_xor(b2, off);
            const float M  = fmaxf(mx, mo);
            const float ea = __expf(mx - M), eb = __expf(mo - M);
            lsum = lsum * ea + lo * eb;
            b0 = b0 * ea + c0 * eb;
            b1 = b1 * ea + c1 * eb;
            b2 = b2 * ea + c2 * eb;
            mx = M;
        }
        if (lane == 0) {
            const float rl = 1.0f / fmaxf(lsum, 1e-30f);
            g_raw[(size_t)(b * KPAD + i) * 3 + 0] = r14_sane(b0 * rl + Gb0);
            g_raw[(size_t)(b * KPAD + i) * 3 + 1] = r14_sane(b1 * rl + Gb1);
            g_raw[(size_t)(b * KPAD + i) * 3 + 2] = r14_sane(b2 * rl + Gb2);
        }
    }
}

// ---------------------------------------------------------------------------
// K4: GraphNorm2 + relu, add-pool, feat gather, dueling head. (verbatim r12)
__global__ __launch_bounds__(512) void r14_head(
    const float* __restrict__ g_raw,
    const float* __restrict__ x1,
    const float* __restrict__ x,
    const int* __restrict__ cnid,
    const int* __restrict__ amask,
    const float* n2w, const float* n2b, const float* n2ms,
    const float* v1w, const float* v1b,
    const float* v2w, const float* v2b,
    const float* v3w, const float* v3b,
    const float* a1w, const float* a1b,
    const float* a2w, const float* a2b,
    const float* a3w, const float* a3b,
    float* __restrict__ out)
{
    __shared__ float rbuf[512];
    __shared__ float mv[6];
    __shared__ float gp[3];
    __shared__ float feat[19];
    __shared__ float h1a[10], h1v[10], h2a[5], h2v[5];
    __shared__ float a3[50];
    __shared__ float vout_s, amean_s;
    const int b = blockIdx.x, t = threadIdx.x;
    const float denom = 1.0f / (float)(BB * KKk);

    float gv0[13], gv1[13], gv2[13];
    float s0 = 0.0f, s1 = 0.0f, s2 = 0.0f;
#pragma unroll
    for (int k = 0; k < 13; ++k) {
        const int r = k * 512 + t;
        float q0 = 0.0f, q1 = 0.0f, q2 = 0.0f;
        if (r < BB * KKk) {
            const int bq = r / KKk, iq = r - bq * KKk;
            const float* gr = g_raw + (size_t)(bq * KPAD + iq) * 3;
            q0 = gr[0]; q1 = gr[1]; q2 = gr[2];
        }
        gv0[k] = q0; gv1[k] = q1; gv2[k] = q2;
        s0 += q0; s1 += q1; s2 += q2;
    }
    float acc[3] = { s0, s1, s2 };
    for (int c = 0; c < 3; ++c) {
        __syncthreads();
        rbuf[t] = acc[c];
        __syncthreads();
        for (int st = 256; st > 0; st >>= 1) {
            if (t < st) rbuf[t] += rbuf[t + st];
            __syncthreads();
        }
        if (t == 0) mv[c] = rbuf[0] * denom;
    }
    __syncthreads();
    const float mm0 = n2ms[0] * mv[0], mm1 = n2ms[1] * mv[1], mm2 = n2ms[2] * mv[2];
    float a0 = 0.0f, a1 = 0.0f, a2 = 0.0f;
#pragma unroll
    for (int k = 0; k < 13; ++k) {
        const int r = k * 512 + t;
        if (r < BB * KKk) {
            const float d0 = gv0[k] - mm0, d1 = gv1[k] - mm1, d2 = gv2[k] - mm2;
            a0 += d0 * d0; a1 += d1 * d1; a2 += d2 * d2;
        }
    }
    float accv[3] = { a0, a1, a2 };
    for (int c = 0; c < 3; ++c) {
        __syncthreads();
        rbuf[t] = accv[c];
        __syncthreads();
        for (int st = 256; st > 0; st >>= 1) {
            if (t < st) rbuf[t] += rbuf[t + st];
            __syncthreads();
        }
        if (t == 0) mv[3 + c] = rbuf[0] * denom;
    }
    __syncthreads();

    const float mmv[3] = { mm0, mm1, mm2 };
    float s3[3] = { 0.0f, 0.0f, 0.0f };
    if (t < KKk) {
        const size_t r = (size_t)(b * KPAD + t) * 3;
#pragma unroll
        for (int c = 0; c < 3; ++c) {
            const float iv = 1.0f / sqrtf(fmaxf(mv[3 + c], 0.0f) + EPSf);
            s3[c] = fmaxf((g_raw[r + c] - mmv[c]) * iv * n2w[c] + n2b[c], 0.0f);
        }
    }
    for (int c = 0; c < 3; ++c) {
        __syncthreads();
        rbuf[t] = s3[c];
        __syncthreads();
        for (int st = 256; st > 0; st >>= 1) {
            if (t < st) rbuf[t] += rbuf[t + st];
            __syncthreads();
        }
        if (t == 0) gp[c] = rbuf[0];
    }
    __syncthreads();

    if (t < 19) {
        const int gidx = cnid[b] + b * KKk;        // faithful: pooled-K offsets
        float fv;
        if (t < 13)      fv = x[(size_t)gidx * NFf + t];
        else if (t < 16) fv = x1[(size_t)gidx * 3 + (t - 13)];
        else             fv = gp[t - 16];
        feat[t] = fv;
    }
    __syncthreads();

    if (t < 10) {
        float s = a1b[t];
        for (int f = 0; f < 19; ++f) s += feat[f] * a1w[f * 10 + t];
        h1a[t] = fmaxf(s, 0.0f);
    } else if (t >= 64 && t < 74) {
        const int j = t - 64;
        float s = v1b[j];
        for (int f = 0; f < 19; ++f) s += feat[f] * v1w[f * 10 + j];
        h1v[j] = fmaxf(s, 0.0f);
    }
    __syncthreads();
    if (t < 5) {
        float s = a2b[t];
        for (int k = 0; k < 10; ++k) s += h1a[k] * a2w[k * 5 + t];
        h2a[t] = fmaxf(s, 0.0f);
    } else if (t >= 64 && t < 69) {
        const int j = t - 64;
        float s = v2b[j];
        for (int k = 0; k < 10; ++k) s += h1v[k] * v2w[k * 5 + j];
        h2v[j] = fmaxf(s, 0.0f);
    }
    __syncthreads();
    if (t < 50) {
        float s = a3b[t];
        for (int k = 0; k < 5; ++k) s += h2a[k] * a3w[k * 50 + t];
        a3[t] = s;
    } else if (t == 64) {
        float s = v3b[0];
        for (int k = 0; k < 5; ++k) s += h2v[k] * v3w[k];
        vout_s = s;
    }
    __syncthreads();
    if (t == 0) {
        float s = 0.0f;
        for (int k = 0; k < 50; ++k) s += a3[k];
        amean_s = s * (1.0f / 50.0f);
    }
    __syncthreads();
    if (t < 50) {
        float q = vout_s + a3[t] - amean_s;
        if (!(q == q)) q = 0.0f;
        q = fminf(fmaxf(q, -QCLMP), QCLMP);
        out[b * NAa + t] = (amask[b * NAa + t] == 0) ? -1e8f : q;   // FP32
    }
}

// ---------------------------------------------------------------------------
extern "C" void kernel_launch(void* const* d_in, const int* in_sizes, int n_in,
                              void* d_out, int out_size, void* d_ws, size_t ws_size,
                              hipStream_t stream) {
    (void)in_sizes; (void)n_in; (void)out_size;
    const float* x     = (const float*)d_in[0];
    const int* ei      = (const int*)d_in[1];
    const int* cnid    = (const int*)d_in[4];
    const int* amask   = (const int*)d_in[5];
    const float* panw  = (const float*)d_in[6];
    const float* l1w   = (const float*)d_in[7];
    const float* l1b   = (const float*)d_in[8];
    const float* n1w   = (const float*)d_in[9];
    const float* n1b   = (const float*)d_in[10];
    const float* n1ms  = (const float*)d_in[11];
    const float* poolp = (const float*)d_in[12];
    const float* poolb = (const float*)d_in[13];
    const float* gwl   = (const float*)d_in[14];
    const float* gbl   = (const float*)d_in[15];
    const float* gwr   = (const float*)d_in[16];
    const float* gbr   = (const float*)d_in[17];
    const float* gatt  = (const float*)d_in[18];
    const float* gbias = (const float*)d_in[19];
    const float* n2w   = (const float*)d_in[20];
    const float* n2b   = (const float*)d_in[21];
    const float* n2ms  = (const float*)d_in[22];
    const float* v1w   = (const float*)d_in[23];
    const float* v1b   = (const float*)d_in[24];
    const float* v2w   = (const float*)d_in[25];
    const float* v2b   = (const float*)d_in[26];
    const float* v3w   = (const float*)d_in[27];
    const float* v3b   = (const float*)d_in[28];
    const float* a1w   = (const float*)d_in[29];
    const float* a1b   = (const float*)d_in[30];
    const float* a2w   = (const float*)d_in[31];
    const float* a2b   = (const float*)d_in[32];
    const float* a3w   = (const float*)d_in[33];
    const float* a3b   = (const float*)d_in[34];
    float* out         = (float*)d_out;

    // ws layout (bytes): fwdb 512K | trsb 512K | Rb 512K | floats
    uint8_t* wsb = (uint8_t*)d_ws;
    uint32_t* fwdb = (uint32_t*)wsb;
    uint32_t* trsb = (uint32_t*)(wsb + 524288);
    uint32_t* Rb   = (uint32_t*)(wsb + 1048576);
    float* h_raw  = (float*)(wsb + 1572864);
    float* x1     = h_raw + (size_t)NNt * 3;
    float* colsum = x1 + (size_t)NNt * 3;
    float* g_raw  = colsum + NNt;
    const size_t needed = 1572864 +
                          ((size_t)(2 * NNt * 3 + NNt + BB * KPAD * 3)) * 4;
    if (ws_size < needed) return;

    hipMemsetAsync(fwdb, 0, 1048576, stream);            // both bitsets
    r14_scatter<<<dim3((EEe + 255) / 256), dim3(256), 0, stream>>>(ei, fwdb, trsb);
    r14_mid<<<dim3(16, 20), dim3(512), 0, stream>>>(x, fwdb, trsb, panw, l1w, l1b,
                                                    h_raw, colsum, Rb);
    r14_poolgat<<<dim3(16), dim3(512), 0, stream>>>(h_raw, colsum, Rb,
                                                    n1w, n1b, n1ms, poolp, poolb,
                                                    gwl, gbl, gwr, gbr, gatt, gbias,
                                                    x1, g_raw);
    r14_head<<<dim3(16), dim3(512), 0, stream>>>(g_raw, x1, x, cnid, amask,
                                                 n2w, n2b, n2ms, v1w, v1b, v2w, v2b, v3w, v3b,
                                                 a1w, a1b, a2w, a2b, a3w, a3b, out);
}

// Round 15
// 225.274 us; speedup vs baseline: 2.8011x; 1.5283x over previous
//
#include <hip/hip_runtime.h>
#include <hip/hip_bf16.h>
#include <stdint.h>
#include <math.h>

// PANConcDQL round 15 -- math identical to rounds 8-14 (passed, absmax 0.0).
// r14 lessons: (a) runtime-indexed idx[] extraction spills to scratch (15MB
// HBM writes) -> keep the separate coalesced CSR-plane extract kernel;
// (b) GAT needs >=64 waves/graph -> poolgat at grid (16,8), not (16,1).
#define BB   16
#define NPn  512
#define LLp  20
#define NAa  50
#define KKk  410
#define NNt  (BB * NPn)   // 8192
#define EEe  (6 * NNt)    // 49152
#define NFf  13
#define KPAD 416
#define EPSf 1e-5f
#define QCLMP 1e6f
#define MAXD 28
#define PADR 512

__device__ __forceinline__ float r15_sane(float v) {
    if (!(v == v)) return 0.0f;
    return fminf(fmaxf(v, -1e15f), 1e15f);
}

// ---------------------------------------------------------------------------
// K1: edge scatter -> global bitsets (fwd: in-neighbors; trs: out-neighbors).
__global__ __launch_bounds__(256) void r15_scatter(
    const int* __restrict__ ei,
    uint32_t* __restrict__ fwdb, uint32_t* __restrict__ trsb)
{
    const int e = blockIdx.x * 256 + threadIdx.x;
    if (e < EEe) {
        const int src = ei[e], dst = ei[EEe + e];
        atomicOr(&fwdb[(size_t)dst * 16 + ((src & 511) >> 5)], 1u << (src & 31));
        atomicOr(&trsb[(size_t)src * 16 + ((dst & 511) >> 5)], 1u << (dst & 31));
    }
}

// ---------------------------------------------------------------------------
// K2: bitset -> CSR planes (u16, csr[j*8192+node], coalesced stores).
__global__ __launch_bounds__(256) void r15_extract(
    const uint32_t* __restrict__ fwdb, const uint32_t* __restrict__ trsb,
    unsigned short* __restrict__ csrF, unsigned short* __restrict__ csrT)
{
    const int t = blockIdx.x * 256 + threadIdx.x;      // 0..16383
    const int node = t & 8191;
    const uint32_t* bs = (t < 8192) ? (fwdb + (size_t)node * 16)
                                    : (trsb + (size_t)node * 16);
    unsigned short* cs = (t < 8192) ? csrF : csrT;
    int cnt = 0;
    for (int w = 0; w < 16; ++w) {
        uint32_t bits = bs[w];
        while (bits) {
            const int u = (w << 5) + __ffs(bits) - 1;
            bits &= bits - 1;
            if (cnt < MAXD) cs[(size_t)cnt * 8192 + node] = (unsigned short)u;
            ++cnt;
        }
    }
    for (int j = cnt; j < MAXD; ++j) cs[(size_t)j * 8192 + node] = PADR;
}

// ---------------------------------------------------------------------------
// K3: mid, grid (16,20) x 512. CSR planes -> registers (compile-time idx).
//  y<4 : deg chain (redundant x4) -> dis; then channel chain
//        (y<3: Y-channel y over csrF -> h_raw; y==3: z over csrT -> colsum)
//  y>=4: closure window q = y-4 over csrF -> Rb
__global__ __launch_bounds__(512) void r15_mid(
    const float* __restrict__ x,
    const unsigned short* __restrict__ csrF,
    const unsigned short* __restrict__ csrT,
    const float* __restrict__ panw,
    const float* __restrict__ l1w, const float* __restrict__ l1b,
    float* __restrict__ h_raw, float* __restrict__ colsum,
    uint32_t* __restrict__ Rb)
{
    __shared__ __align__(16) uint32_t sbuf[1047];
    float* pa  = (float*)sbuf;             // 513
    float* pb  = (float*)(sbuf + 513);     // 513
    float* wsh = (float*)(sbuf + 1026);    // 21
    const int b = blockIdx.x, y = blockIdx.y, t = threadIdx.x;
    const int node = b * 512 + t;

    if (y < 4) {
        const int c = y;
        int iF[MAXD];
#pragma unroll
        for (int j = 0; j < MAXD; ++j) iF[j] = (int)csrF[(size_t)j * 8192 + node];
        if (t < 21) wsh[t] = panw[t];

        // deg chain over iF
        pa[t] = 1.0f;
        if (t == 0) { pa[512] = 0.0f; pb[512] = 0.0f; }
        __syncthreads();
        float dacc = wsh[0];
        {
            float* rp = pa; float* rn = pb;
            for (int i = 1; i <= LLp; ++i) {
                float tv[MAXD];
#pragma unroll
                for (int j = 0; j < MAXD; ++j) tv[j] = rp[iF[j]];
                float s = 0.0f;
#pragma unroll
                for (int j = 0; j < MAXD; ++j) s += tv[j];
                rn[t] = s;
                dacc += wsh[i] * s;
                __syncthreads();
                float* tp = rp; rp = rn; rn = tp;
            }
        }
        const float d0 = (dacc > 0.0f) ? 1.0f / sqrtf(dacc) : 0.0f;

        // channel chain
        int idx[MAXD];
        if (c == 3) {
#pragma unroll
            for (int j = 0; j < MAXD; ++j) idx[j] = (int)csrT[(size_t)j * 8192 + node];
        } else {
#pragma unroll
            for (int j = 0; j < MAXD; ++j) idx[j] = iF[j];
        }
        float seed;
        if (c < 3) {
            float xw = 0.0f;
            const float* xr = x + (size_t)node * NFf;
            for (int f = 0; f < NFf; ++f) xw += xr[f] * l1w[f * 3 + c];
            seed = d0 * xw;
        } else {
            seed = d0;
        }
        pa[t] = seed;
        if (t == 0) { pa[512] = 0.0f; pb[512] = 0.0f; }
        __syncthreads();
        float acc = wsh[0] * seed;
        {
            float* rp = pa; float* rn = pb;
            for (int i = 1; i <= LLp; ++i) {
                float tv[MAXD];
#pragma unroll
                for (int j = 0; j < MAXD; ++j) tv[j] = rp[idx[j]];
                float s = 0.0f;
#pragma unroll
                for (int j = 0; j < MAXD; ++j) s += tv[j];
                rn[t] = s;
                acc += wsh[i] * s;
                __syncthreads();
                float* tp = rp; rp = rn; rn = tp;
            }
        }
        if (c < 3) h_raw[(size_t)node * 3 + c] = r15_sane(d0 * acc + l1b[c]);
        else       colsum[node] = r15_sane(d0 * acc);
    } else {
        const int q = y - 4;
        int iF[MAXD];
#pragma unroll
        for (int j = 0; j < MAXD; ++j) iF[j] = (int)csrF[(size_t)j * 8192 + node];
        uint32_t* R1 = sbuf;
        uint32_t* R2 = sbuf + 513;
        R1[t] = ((t >> 5) == q) ? (1u << (t & 31)) : 0u;
        if (t == 0) { R1[512] = 0u; R2[512] = 0u; }
        __syncthreads();
        uint32_t* Rp = R1; uint32_t* Rn = R2;
        for (int i = 0; i < LLp; ++i) {
            uint32_t tv[MAXD];
#pragma unroll
            for (int j = 0; j < MAXD; ++j) tv[j] = Rp[iF[j]];
            uint32_t r = Rp[t];
#pragma unroll
            for (int j = 0; j < MAXD; ++j) r |= tv[j];
            Rn[t] = r;
            __syncthreads();
            uint32_t* tp = Rp; Rp = Rn; Rn = tp;
        }
        Rb[(size_t)node * 16 + q] = Rp[t];
    }
}

// ---------------------------------------------------------------------------
// K4: poolgat, grid (16,8) x 512. Pool computed redundantly per block (LDS-
// resident kept/xp); GAT rows split over 64 waves/graph (<=7 rows/wave).
__global__ __launch_bounds__(512) void r15_poolgat(
    const float* __restrict__ h_raw,
    const float* __restrict__ colsum,
    const uint32_t* __restrict__ Rb,
    const float* n1w, const float* n1b, const float* n1ms,
    const float* poolp, const float* poolb,
    const float* gwl, const float* gbl,
    const float* gwr, const float* gbr,
    const float* gatt, const float* gbias,
    float* __restrict__ x1,
    float* __restrict__ g_raw)
{
    __shared__ __align__(16) uint32_t pg[10592];
    float* red  = (float*)pg;                  // 512
    float* sc   = (float*)(pg + 512);          // 512
    float* mv   = (float*)(pg + 1024);         // 8
    float* xpS  = (float*)(pg + 1032);         // 1248 (416*3)
    int*   kidx = (int*)(pg + 2280);           // 416
    float* xlS  = (float*)(pg + 2696);         // 1232
    uint32_t* RT = pg + 3928;                  // 16*416 = 6656
    const int b = blockIdx.x, y = blockIdx.y, t = threadIdx.x;
    const float inv_n = 1.0f / (float)NNt;

    // ---- pool: norm1 stats (two-pass, register-cached rows) ----
    float hv0[16], hv1[16], hv2[16];
    float s0 = 0.0f, s1 = 0.0f, s2 = 0.0f;
#pragma unroll
    for (int k = 0; k < 16; ++k) {
        const float* hr = h_raw + (size_t)(k * 512 + t) * 3;
        hv0[k] = hr[0]; hv1[k] = hr[1]; hv2[k] = hr[2];
        s0 += hv0[k]; s1 += hv1[k]; s2 += hv2[k];
    }
    float acc[3] = { s0, s1, s2 };
    for (int c = 0; c < 3; ++c) {
        __syncthreads();
        red[t] = acc[c];
        __syncthreads();
        for (int st = 256; st > 0; st >>= 1) {
            if (t < st) red[t] += red[t + st];
            __syncthreads();
        }
        if (t == 0) mv[c] = red[0] * inv_n;
    }
    __syncthreads();
    const float mm0 = n1ms[0] * mv[0], mm1 = n1ms[1] * mv[1], mm2 = n1ms[2] * mv[2];
    float a0 = 0.0f, a1 = 0.0f, a2 = 0.0f;
#pragma unroll
    for (int k = 0; k < 16; ++k) {
        const float d0 = hv0[k] - mm0, d1 = hv1[k] - mm1, d2 = hv2[k] - mm2;
        a0 += d0 * d0; a1 += d1 * d1; a2 += d2 * d2;
    }
    float accv[3] = { a0, a1, a2 };
    for (int c = 0; c < 3; ++c) {
        __syncthreads();
        red[t] = accv[c];
        __syncthreads();
        for (int st = 256; st > 0; st >>= 1) {
            if (t < st) red[t] += red[t + st];
            __syncthreads();
        }
        if (t == 0) mv[3 + c] = red[0] * inv_n;
    }
    __syncthreads();

    const float mmv[3] = { mm0, mm1, mm2 };
    float xv[3];
#pragma unroll
    for (int c = 0; c < 3; ++c) {
        const float iv = 1.0f / sqrtf(fmaxf(mv[3 + c], 0.0f) + EPSf);
        const float o  = h_raw[(size_t)(b * NPn + t) * 3 + c] - mmv[c];
        const float tt = n1w[c] * o * iv + n1b[c];
        xv[c] = fmaxf(tt, 0.0f);
        if (y == 0) x1[(size_t)(b * NPn + t) * 3 + c] = xv[c];
    }
    float s = poolb[0] * (xv[0] * poolp[0] + xv[1] * poolp[1] + xv[2] * poolp[2])
            + poolb[1] * colsum[b * NPn + t];
    s = tanhf(s);
    if (!(s == s)) s = 0.0f;
    sc[t] = s;
    __syncthreads();
    int cnt = 0;
    for (int u = 0; u < NPn; ++u) {
        const float su = sc[u];
        cnt += ((su > s) || (su == s && u < t)) ? 1 : 0;   // lax.top_k tie-break
    }
    if (cnt < KKk) {                       // rank-count bijection: each slot once
        kidx[cnt] = t;
        xpS[cnt * 3 + 0] = xv[0] * s;
        xpS[cnt * 3 + 1] = xv[1] * s;
        xpS[cnt * 3 + 2] = xv[2] * s;
    }
    __syncthreads();

    // ---- GAT staging ----
    float Wl[9], Wr[9];
#pragma unroll
    for (int i2 = 0; i2 < 9; ++i2) { Wl[i2] = gwl[i2]; Wr[i2] = gwr[i2]; }
    const float Bl0 = gbl[0], Bl1 = gbl[1], Bl2 = gbl[2];
    const float Br0 = gbr[0], Br1 = gbr[1], Br2 = gbr[2];
    const float At0 = gatt[0], At1 = gatt[1], At2 = gatt[2];
    const float Gb0 = gbias[0], Gb1 = gbias[1], Gb2 = gbias[2];
    for (int j = t; j < KKk; j += 512) {
        const float p0 = xpS[j * 3 + 0];
        const float p1 = xpS[j * 3 + 1];
        const float p2 = xpS[j * 3 + 2];
        xlS[j * 3 + 0] = p0 * Wl[0] + p1 * Wl[3] + p2 * Wl[6] + Bl0;
        xlS[j * 3 + 1] = p0 * Wl[1] + p1 * Wl[4] + p2 * Wl[7] + Bl1;
        xlS[j * 3 + 2] = p0 * Wl[2] + p1 * Wl[5] + p2 * Wl[8] + Bl2;
        const uint32_t* rr = Rb + (size_t)(b * NPn + kidx[j]) * 16;
#pragma unroll
        for (int w = 0; w < 16; ++w) RT[w * KPAD + j] = rr[w];
    }
    __syncthreads();

    // ---- GAT rows: 64 waves/graph; wave wid handles i = wid, wid+64 ... ----
    const int lane = t & 63, wv = t >> 6;
    const int wid = y * 8 + wv;                    // 0..63
    for (int i = wid; i < KKk; i += 64) {
        const float p0 = xpS[i * 3 + 0];
        const float p1 = xpS[i * 3 + 1];
        const float p2 = xpS[i * 3 + 2];
        const float xr0 = p0 * Wr[0] + p1 * Wr[3] + p2 * Wr[6] + Br0;
        const float xr1 = p0 * Wr[1] + p1 * Wr[4] + p2 * Wr[7] + Br1;
        const float xr2 = p0 * Wr[2] + p1 * Wr[5] + p2 * Wr[8] + Br2;
        const int bi = kidx[i];
        const uint32_t mbit = 1u << (bi & 31);
        const uint32_t* Rw = &RT[(bi >> 5) * KPAD];
        float mx = -3e38f, lsum = 0.0f, b0 = 0.0f, b1 = 0.0f, b2 = 0.0f;
        for (int j = lane; j < KKk; j += 64) {     // <=7 iters/lane
            if ((Rw[j] & mbit) || (j == i)) {
                float e0 = xr0 + xlS[j * 3 + 0]; e0 = e0 > 0.0f ? e0 : 0.2f * e0;
                float e1 = xr1 + xlS[j * 3 + 1]; e1 = e1 > 0.0f ? e1 : 0.2f * e1;
                float e2 = xr2 + xlS[j * 3 + 2]; e2 = e2 > 0.0f ? e2 : 0.2f * e2;
                const float sv = At0 * e0 + At1 * e1 + At2 * e2;
                if (sv > mx) {
                    const float r = __expf(mx - sv);
                    lsum *= r; b0 *= r; b1 *= r; b2 *= r;
                    mx = sv;
                }
                const float pj = __expf(sv - mx);
                lsum += pj;
                b0 += pj * xlS[j * 3 + 0];
                b1 += pj * xlS[j * 3 + 1];
                b2 += pj * xlS[j * 3 + 2];
            }
        }
        for (int off = 32; off; off >>= 1) {       // butterfly LSE merge
            const float mo = __shfl_xor(mx, off);
            const float lo = __shfl_xor(lsum, off);
            const float c0 = __shfl_xor(b0, off);
            const float c1 = __shfl_xor(b1, off);
            const float c2 = __shfl_xor(b2, off);
            const float M  = fmaxf(mx, mo);
            const float ea = __expf(mx - M), eb = __expf(mo - M);
            lsum = lsum * ea + lo * eb;
            b0 = b0 * ea + c0 * eb;
            b1 = b1 * ea + c1 * eb;
            b2 = b2 * ea + c2 * eb;
            mx = M;
        }
        if (lane == 0) {
            const float rl = 1.0f / fmaxf(lsum, 1e-30f);
            g_raw[(size_t)(b * KPAD + i) * 3 + 0] = r15_sane(b0 * rl + Gb0);
            g_raw[(size_t)(b * KPAD + i) * 3 + 1] = r15_sane(b1 * rl + Gb1);
            g_raw[(size_t)(b * KPAD + i) * 3 + 2] = r15_sane(b2 * rl + Gb2);
        }
    }
}

// ---------------------------------------------------------------------------
// K5: GraphNorm2 + relu, add-pool, feat gather, dueling head. (verbatim r12)
__global__ __launch_bounds__(512) void r15_head(
    const float* __restrict__ g_raw,
    const float* __restrict__ x1,
    const float* __restrict__ x,
    const int* __restrict__ cnid,
    const int* __restrict__ amask,
    const float* n2w, const float* n2b, const float* n2ms,
    const float* v1w, const float* v1b,
    const float* v2w, const float* v2b,
    const float* v3w, const float* v3b,
    const float* a1w, const float* a1b,
    const float* a2w, const float* a2b,
    const float* a3w, const float* a3b,
    float* __restrict__ out)
{
    __shared__ float rbuf[512];
    __shared__ float mv[6];
    __shared__ float gp[3];
    __shared__ float feat[19];
    __shared__ float h1a[10], h1v[10], h2a[5], h2v[5];
    __shared__ float a3[50];
    __shared__ float vout_s, amean_s;
    const int b = blockIdx.x, t = threadIdx.x;
    const float denom = 1.0f / (float)(BB * KKk);

    float gv0[13], gv1[13], gv2[13];
    float s0 = 0.0f, s1 = 0.0f, s2 = 0.0f;
#pragma unroll
    for (int k = 0; k < 13; ++k) {
        const int r = k * 512 + t;
        float q0 = 0.0f, q1 = 0.0f, q2 = 0.0f;
        if (r < BB * KKk) {
            const int bq = r / KKk, iq = r - bq * KKk;
            const float* gr = g_raw + (size_t)(bq * KPAD + iq) * 3;
            q0 = gr[0]; q1 = gr[1]; q2 = gr[2];
        }
        gv0[k] = q0; gv1[k] = q1; gv2[k] = q2;
        s0 += q0; s1 += q1; s2 += q2;
    }
    float acc[3] = { s0, s1, s2 };
    for (int c = 0; c < 3; ++c) {
        __syncthreads();
        rbuf[t] = acc[c];
        __syncthreads();
        for (int st = 256; st > 0; st >>= 1) {
            if (t < st) rbuf[t] += rbuf[t + st];
            __syncthreads();
        }
        if (t == 0) mv[c] = rbuf[0] * denom;
    }
    __syncthreads();
    const float mm0 = n2ms[0] * mv[0], mm1 = n2ms[1] * mv[1], mm2 = n2ms[2] * mv[2];
    float a0 = 0.0f, a1 = 0.0f, a2 = 0.0f;
#pragma unroll
    for (int k = 0; k < 13; ++k) {
        const int r = k * 512 + t;
        if (r < BB * KKk) {
            const float d0 = gv0[k] - mm0, d1 = gv1[k] - mm1, d2 = gv2[k] - mm2;
            a0 += d0 * d0; a1 += d1 * d1; a2 += d2 * d2;
        }
    }
    float accv[3] = { a0, a1, a2 };
    for (int c = 0; c < 3; ++c) {
        __syncthreads();
        rbuf[t] = accv[c];
        __syncthreads();
        for (int st = 256; st > 0; st >>= 1) {
            if (t < st) rbuf[t] += rbuf[t + st];
            __syncthreads();
        }
        if (t == 0) mv[3 + c] = rbuf[0] * denom;
    }
    __syncthreads();

    const float mmv[3] = { mm0, mm1, mm2 };
    float s3[3] = { 0.0f, 0.0f, 0.0f };
    if (t < KKk) {
        const size_t r = (size_t)(b * KPAD + t) * 3;
#pragma unroll
        for (int c = 0; c < 3; ++c) {
            const float iv = 1.0f / sqrtf(fmaxf(mv[3 + c], 0.0f) + EPSf);
            s3[c] = fmaxf((g_raw[r + c] - mmv[c]) * iv * n2w[c] + n2b[c], 0.0f);
        }
    }
    for (int c = 0; c < 3; ++c) {
        __syncthreads();
        rbuf[t] = s3[c];
        __syncthreads();
        for (int st = 256; st > 0; st >>= 1) {
            if (t < st) rbuf[t] += rbuf[t + st];
            __syncthreads();
        }
        if (t == 0) gp[c] = rbuf[0];
    }
    __syncthreads();

    if (t < 19) {
        const int gidx = cnid[b] + b * KKk;        // faithful: pooled-K offsets
        float fv;
        if (t < 13)      fv = x[(size_t)gidx * NFf + t];
        else if (t < 16) fv = x1[(size_t)gidx * 3 + (t - 13)];
        else             fv = gp[t - 16];
        feat[t] = fv;
    }
    __syncthreads();

    if (t < 10) {
        float s = a1b[t];
        for (int f = 0; f < 19; ++f) s += feat[f] * a1w[f * 10 + t];
        h1a[t] = fmaxf(s, 0.0f);
    } else if (t >= 64 && t < 74) {
        const int j = t - 64;
        float s = v1b[j];
        for (int f = 0; f < 19; ++f) s += feat[f] * v1w[f * 10 + j];
        h1v[j] = fmaxf(s, 0.0f);
    }
    __syncthreads();
    if (t < 5) {
        float s = a2b[t];
        for (int k = 0; k < 10; ++k) s += h1a[k] * a2w[k * 5 + t];
        h2a[t] = fmaxf(s, 0.0f);
    } else if (t >= 64 && t < 69) {
        const int j = t - 64;
        float s = v2b[j];
        for (int k = 0; k < 10; ++k) s += h1v[k] * v2w[k * 5 + j];
        h2v[j] = fmaxf(s, 0.0f);
    }
    __syncthreads();
    if (t < 50) {
        float s = a3b[t];
        for (int k = 0; k < 5; ++k) s += h2a[k] * a3w[k * 50 + t];
        a3[t] = s;
    } else if (t == 64) {
        float s = v3b[0];
        for (int k = 0; k < 5; ++k) s += h2v[k] * v3w[k];
        vout_s = s;
    }
    __syncthreads();
    if (t == 0) {
        float s = 0.0f;
        for (int k = 0; k < 50; ++k) s += a3[k];
        amean_s = s * (1.0f / 50.0f);
    }
    __syncthreads();
    if (t < 50) {
        float q = vout_s + a3[t] - amean_s;
        if (!(q == q)) q = 0.0f;
        q = fminf(fmaxf(q, -QCLMP), QCLMP);
        out[b * NAa + t] = (amask[b * NAa + t] == 0) ? -1e8f : q;   // FP32
    }
}

// ---------------------------------------------------------------------------
extern "C" void kernel_launch(void* const* d_in, const int* in_sizes, int n_in,
                              void* d_out, int out_size, void* d_ws, size_t ws_size,
                              hipStream_t stream) {
    (void)in_sizes; (void)n_in; (void)out_size;
    const float* x     = (const float*)d_in[0];
    const int* ei      = (const int*)d_in[1];
    const int* cnid    = (const int*)d_in[4];
    const int* amask   = (const int*)d_in[5];
    const float* panw  = (const float*)d_in[6];
    const float* l1w   = (const float*)d_in[7];
    const float* l1b   = (const float*)d_in[8];
    const float* n1w   = (const float*)d_in[9];
    const float* n1b   = (const float*)d_in[10];
    const float* n1ms  = (const float*)d_in[11];
    const float* poolp = (const float*)d_in[12];
    const float* poolb = (const float*)d_in[13];
    const float* gwl   = (const float*)d_in[14];
    const float* gbl   = (const float*)d_in[15];
    const float* gwr   = (const float*)d_in[16];
    const float* gbr   = (const float*)d_in[17];
    const float* gatt  = (const float*)d_in[18];
    const float* gbias = (const float*)d_in[19];
    const float* n2w   = (const float*)d_in[20];
    const float* n2b   = (const float*)d_in[21];
    const float* n2ms  = (const float*)d_in[22];
    const float* v1w   = (const float*)d_in[23];
    const float* v1b   = (const float*)d_in[24];
    const float* v2w   = (const float*)d_in[25];
    const float* v2b   = (const float*)d_in[26];
    const float* v3w   = (const float*)d_in[27];
    const float* v3b   = (const float*)d_in[28];
    const float* a1w   = (const float*)d_in[29];
    const float* a1b   = (const float*)d_in[30];
    const float* a2w   = (const float*)d_in[31];
    const float* a2b   = (const float*)d_in[32];
    const float* a3w   = (const float*)d_in[33];
    const float* a3b   = (const float*)d_in[34];
    float* out         = (float*)d_out;

    // ws layout (bytes): fwdb 512K | trsb 512K | Rb 512K | csrF | csrT | floats
    uint8_t* wsb = (uint8_t*)d_ws;
    uint32_t* fwdb = (uint32_t*)wsb;
    uint32_t* trsb = (uint32_t*)(wsb + 524288);
    uint32_t* Rb   = (uint32_t*)(wsb + 1048576);
    unsigned short* csrF = (unsigned short*)(wsb + 1572864);
    unsigned short* csrT = csrF + (size_t)MAXD * 8192;
    float* h_raw  = (float*)(csrT + (size_t)MAXD * 8192);
    float* x1     = h_raw + (size_t)NNt * 3;
    float* colsum = x1 + (size_t)NNt * 3;
    float* g_raw  = colsum + NNt;
    const size_t needed = 1572864 + 2 * (size_t)MAXD * 8192 * 2 +
                          ((size_t)(2 * NNt * 3 + NNt + BB * KPAD * 3)) * 4;
    if (ws_size < needed) return;

    hipMemsetAsync(fwdb, 0, 1048576, stream);            // both bitsets
    r15_scatter<<<dim3((EEe + 255) / 256), dim3(256), 0, stream>>>(ei, fwdb, trsb);
    r15_extract<<<dim3(64), dim3(256), 0, stream>>>(fwdb, trsb, csrF, csrT);
    r15_mid<<<dim3(16, 20), dim3(512), 0, stream>>>(x, csrF, csrT, panw, l1w, l1b,
                                                    h_raw, colsum, Rb);
    r15_poolgat<<<dim3(16, 8), dim3(512), 0, stream>>>(h_raw, colsum, Rb,
                                                       n1w, n1b, n1ms, poolp, poolb,
                                                       gwl, gbl, gwr, gbr, gatt, gbias,
                                                       x1, g_raw);
    r15_head<<<dim3(16), dim3(512), 0, stream>>>(g_raw, x1, x, cnid, amask,
                                                 n2w, n2b, n2ms, v1w, v1b, v2w, v2b, v3w, v3b,
                                                 a1w, a1b, a2w, a2b, a3w, a3b, out);
}